// Round 1
// baseline (843.301 us; speedup 1.0000x reference)
//
#include <hip/hip_runtime.h>
#include <hip/hip_bf16.h>

#define DI __device__ __forceinline__

typedef __attribute__((ext_vector_type(8))) __bf16 bf16x8;
typedef __attribute__((ext_vector_type(4))) float f32x4;
typedef __attribute__((ext_vector_type(2))) float f32x2;
typedef __attribute__((ext_vector_type(8))) unsigned short us8;

// ---- problem constants ----
constexpr int CBATCH = 8;
constexpr int HW = 64;          // H == W
constexpr int CDIM = 384;
constexpr int HEADS = 12;
constexpr int WS = 14;
constexpr int NTOK = 196;       // WS*WS
constexpr int NWIN = 200;       // 8 * 5 * 5
constexpr int MV = 39200;       // NWIN * NTOK
constexpr int MPAD = 39296;     // 307 * 128
constexpr int NQKV = 1152;
constexpr int HIDD = 1536;
constexpr int MMLP = 32768;     // 8 * 4096
constexpr float SCALE = 0.17677669529663687f;  // 32^-0.5

DI unsigned short f2bf(float f) { __bf16 b = (__bf16)f; return __builtin_bit_cast(unsigned short, b); }
DI bf16x8 ldfrag(const unsigned short* p) { return __builtin_bit_cast(bf16x8, *(const us8*)p); }
DI f32x4 mfma16(bf16x8 a, bf16x8 b, f32x4 c) {
  return __builtin_amdgcn_mfma_f32_16x16x32_bf16(a, b, c, 0, 0, 0);
}
DI void async16(const void* g, void* l) {
  __builtin_amdgcn_global_load_lds((const __attribute__((address_space(1))) void*)g,
                                   (__attribute__((address_space(3))) void*)l, 16, 0, 0);
}

// ---------- small prep kernels ----------
__global__ __launch_bounds__(256) void k_cvt(const float* __restrict__ s,
                                             unsigned short* __restrict__ d, int n) {
  int i = blockIdx.x * 256 + threadIdx.x;
  if (i < n) d[i] = f2bf(s[i]);
}

__global__ __launch_bounds__(256) void k_bias(const float* __restrict__ ab,
                                              const int* __restrict__ bidx,
                                              float* __restrict__ bm, int n_off) {
  int i = blockIdx.x * 256 + threadIdx.x;
  if (i < HEADS * NTOK * NTOK) {
    int h = i / (NTOK * NTOK);
    int ij = i - h * (NTOK * NTOK);
    bm[i] = ab[h * n_off + bidx[ij]];
  }
}

// ---------- LayerNorm (one wave per row, 6 f32/lane) ----------
template <int WIN>
__global__ __launch_bounds__(256) void k_ln(const float* __restrict__ src,
                                            const float* __restrict__ lw,
                                            const float* __restrict__ lb,
                                            unsigned short* __restrict__ dst) {
  const int row = blockIdx.x * 4 + (threadIdx.x >> 6);
  const int l = threadIdx.x & 63;
  const int c0 = l * 6;
  const float* p;
  bool valid;
  if (WIN) {
    int win = row / 196, t = row - win * 196;
    int b = win / 25, wi = win - b * 25;
    int wr = wi / 5, wc = wi - wr * 5;
    int hh = wr * 14 + t / 14, ww = wc * 14 + (t - (t / 14) * 14);
    valid = (row < MV) && (hh < HW) && (ww < HW);
    p = src + ((size_t)b * 4096 + hh * 64 + ww) * CDIM;
  } else {
    valid = true;
    p = src + (size_t)row * CDIM;
  }
  float v[6];
  if (valid) {
    f32x2 a = *(const f32x2*)(p + c0);
    f32x2 b2 = *(const f32x2*)(p + c0 + 2);
    f32x2 c2 = *(const f32x2*)(p + c0 + 4);
    v[0] = a.x; v[1] = a.y; v[2] = b2.x; v[3] = b2.y; v[4] = c2.x; v[5] = c2.y;
  } else {
#pragma unroll
    for (int k = 0; k < 6; ++k) v[k] = 0.f;
  }
  float s = 0.f, q = 0.f;
#pragma unroll
  for (int k = 0; k < 6; ++k) { s += v[k]; q += v[k] * v[k]; }
#pragma unroll
  for (int m = 1; m <= 32; m <<= 1) {
    s += __shfl_xor(s, m, 64);
    q += __shfl_xor(q, m, 64);
  }
  float mean = s * (1.0f / 384.0f);
  float var = q * (1.0f / 384.0f) - mean * mean;
  float rs = rsqrtf(var + 1e-5f);
#pragma unroll
  for (int k = 0; k < 6; ++k) {
    float y = (v[k] - mean) * rs * lw[c0 + k] + lb[c0 + k];
    dst[(size_t)row * CDIM + c0 + k] = f2bf(y);
  }
}

// ---------- depthwise 3x3 conv + BN ----------
__global__ __launch_bounds__(256) void k_conv(const float* __restrict__ x1,
                                              const float* __restrict__ cw,
                                              const float* __restrict__ bw,
                                              const float* __restrict__ bb,
                                              const float* __restrict__ bm,
                                              const float* __restrict__ bv,
                                              float* __restrict__ x2) {
  int idx = blockIdx.x * 256 + threadIdx.x;  // b*64*384 + x*384 + c
  int c = idx % 384;
  int x = (idx / 384) & 63;
  int b = idx / (384 * 64);
  const float* base = x1 + (size_t)b * 4096 * 384 + c;
  float w[9];
#pragma unroll
  for (int k = 0; k < 9; ++k) w[k] = cw[c * 9 + k];
  float sc = rsqrtf(bv[c] + 1e-5f) * bw[c];
  float sb = bb[c] - bm[c] * sc;
  float t0m = 0.f, t0c = 0.f, t0p = 0.f;
  float t1m, t1c, t1p, t2m, t2c, t2p;
  t1m = (x > 0) ? base[(x - 1) * 384] : 0.f;
  t1c = base[x * 384];
  t1p = (x < 63) ? base[(x + 1) * 384] : 0.f;
  for (int y = 0; y < 64; ++y) {
    if (y < 63) {
      int ro = (y + 1) * 64;
      t2m = (x > 0) ? base[(ro + x - 1) * 384] : 0.f;
      t2c = base[(ro + x) * 384];
      t2p = (x < 63) ? base[(ro + x + 1) * 384] : 0.f;
    } else { t2m = t2c = t2p = 0.f; }
    float o = w[0] * t0m + w[1] * t0c + w[2] * t0p +
              w[3] * t1m + w[4] * t1c + w[5] * t1p +
              w[6] * t2m + w[7] * t2c + w[8] * t2p;
    x2[((size_t)b * 4096 + y * 64 + x) * 384 + c] = o * sc + sb;
    t0m = t1m; t0c = t1c; t0p = t1p;
    t1m = t2m; t1c = t2c; t1p = t2p;
  }
}

// ---------- fused windowed attention: one block per (window, head) ----------
__global__ __launch_bounds__(256) void k_attn(const unsigned short* __restrict__ qkv,
                                              const float* __restrict__ biasmat,
                                              unsigned short* __restrict__ aout) {
  __shared__ unsigned short Kb[208 * 32];
  __shared__ unsigned short Vt[32 * 232];
  __shared__ unsigned short Pl[4][16 * 232];
  const int blk = blockIdx.x;
  const int win = blk / 12, h = blk - win * 12;
  const int tid = threadIdx.x;
  const int w = tid >> 6, l = tid & 63;
  const int l15 = l & 15, g = l >> 4;
  const unsigned short* qb = qkv + (size_t)win * 196 * 1152 + h * 96;

  // stage K (rows >=196 zeroed)
  for (int i = tid; i < 832; i += 256) {
    int t = i >> 2, d8 = (i & 3) << 3;
    us8 z = {0, 0, 0, 0, 0, 0, 0, 0};
    if (t < 196) z = *(const us8*)(qb + (size_t)t * 1152 + 32 + d8);
    *(us8*)&Kb[t * 32 + d8] = z;
  }
  // stage V transposed Vt[d][t] (cols 196..223 zeroed)
  for (int i = tid; i < 896; i += 256) {
    int t = i >> 2, d8 = (i & 3) << 3;
    us8 z = {0, 0, 0, 0, 0, 0, 0, 0};
    if (t < 196) z = *(const us8*)(qb + (size_t)t * 1152 + 64 + d8);
#pragma unroll
    for (int j = 0; j < 8; ++j) Vt[(d8 + j) * 232 + t] = z[j];
  }
  // zero P pad cols 208..231 (per wave)
  for (int z = l; z < 16 * 24; z += 64) {
    int rr = z / 24, cc = 208 + (z - rr * 24);
    Pl[w][rr * 232 + cc] = 0;
  }
  __syncthreads();

  const float* bmh = biasmat + (size_t)h * (NTOK * NTOK);
  for (int qt = w; qt < 13; qt += 4) {
    // Q fragment straight from global (L2-resident)
    us8 aqr = {0, 0, 0, 0, 0, 0, 0, 0};
    int qrow = qt * 16 + l15;
    if (qrow < 196) aqr = *(const us8*)(qb + (size_t)qrow * 1152 + g * 8);
    bf16x8 aq = __builtin_bit_cast(bf16x8, aqr);

    f32x4 s[13];
#pragma unroll
    for (int kt = 0; kt < 13; ++kt) {
      f32x4 zz = {0.f, 0.f, 0.f, 0.f};
      bf16x8 bk = ldfrag(&Kb[(kt * 16 + l15) * 32 + g * 8]);
      s[kt] = mfma16(aq, bk, zz);
    }
    // scale + bias + mask
#pragma unroll
    for (int kt = 0; kt < 13; ++kt) {
      int col = kt * 16 + l15;
#pragma unroll
      for (int r = 0; r < 4; ++r) {
        int rw = qt * 16 + g * 4 + r;
        float v = s[kt][r] * SCALE;
        if (col < 196) {
          if (rw < 196) v += bmh[rw * 196 + col];
        } else {
          v = -1e30f;
        }
        s[kt][r] = v;
      }
    }
    // softmax along 13 regs x 16 lanes of the group
    float sminv[4];
#pragma unroll
    for (int r = 0; r < 4; ++r) {
      float m = s[0][r];
#pragma unroll
      for (int kt = 1; kt < 13; ++kt) m = fmaxf(m, s[kt][r]);
      m = fmaxf(m, __shfl_xor(m, 1, 64));
      m = fmaxf(m, __shfl_xor(m, 2, 64));
      m = fmaxf(m, __shfl_xor(m, 4, 64));
      m = fmaxf(m, __shfl_xor(m, 8, 64));
      float su = 0.f;
#pragma unroll
      for (int kt = 0; kt < 13; ++kt) {
        float p = __expf(s[kt][r] - m);
        s[kt][r] = p;
        su += p;
      }
      su += __shfl_xor(su, 1, 64);
      su += __shfl_xor(su, 2, 64);
      su += __shfl_xor(su, 4, 64);
      su += __shfl_xor(su, 8, 64);
      sminv[r] = 1.0f / su;
    }
    // write P (bf16) to per-wave LDS
#pragma unroll
    for (int kt = 0; kt < 13; ++kt)
#pragma unroll
      for (int r = 0; r < 4; ++r)
        Pl[w][(g * 4 + r) * 232 + kt * 16 + l15] = f2bf(s[kt][r] * sminv[r]);
    asm volatile("s_waitcnt lgkmcnt(0)" ::: "memory");
    __builtin_amdgcn_sched_barrier(0);
    // PV
    f32x4 o0 = {0.f, 0.f, 0.f, 0.f}, o1 = {0.f, 0.f, 0.f, 0.f};
#pragma unroll
    for (int kc = 0; kc < 7; ++kc) {
      bf16x8 pa = ldfrag(&Pl[w][l15 * 232 + kc * 32 + g * 8]);
      bf16x8 b0 = ldfrag(&Vt[l15 * 232 + kc * 32 + g * 8]);
      bf16x8 b1 = ldfrag(&Vt[(16 + l15) * 232 + kc * 32 + g * 8]);
      o0 = mfma16(pa, b0, o0);
      o1 = mfma16(pa, b1, o1);
    }
#pragma unroll
    for (int r = 0; r < 4; ++r) {
      int rw = qt * 16 + g * 4 + r;
      if (rw < 196) {
        size_t rb = ((size_t)win * 196 + rw) * 384 + h * 32;
        aout[rb + l15] = f2bf(o0[r]);
        aout[rb + 16 + l15] = f2bf(o1[r]);
      }
    }
  }
}

// ---------- bf16 GEMM, B^T weights, 128x128 tile, BK=64, templated epilogue ----
// MODE 0: +bias -> bf16 out (stride NQKV)
// MODE 1: +bias, window-reverse scatter, x1 = x + val (f32)
// MODE 2: +bias, exact GELU -> bf16 out (stride HIDD)
// MODE 3: +bias, out = auxr + val (f32, stride 384)
template <int MODE>
__global__ __launch_bounds__(256) void k_gemm(const unsigned short* __restrict__ A,
                                              const unsigned short* __restrict__ B,
                                              const float* __restrict__ bias,
                                              const float* __restrict__ auxr,
                                              float* __restrict__ auxw,
                                              unsigned short* __restrict__ outb,
                                              int K) {
  __shared__ unsigned short As[128 * 64];
  __shared__ unsigned short Bs[128 * 64];
  const int tid = threadIdx.x;
  const int w = tid >> 6, l = tid & 63;
  const int l15 = l & 15, g = l >> 4;
  const int wm = w >> 1, wn = w & 1;
  const size_t arow0 = (size_t)blockIdx.x * 128;
  const size_t brow0 = (size_t)blockIdx.y * 128;
  f32x4 acc[4][4] = {};
  for (int ks = 0; ks < K; ks += 64) {
    if (ks) __syncthreads();
#pragma unroll
    for (int it = 0; it < 4; ++it) {
      const int f = it * 256 + tid;
      const int r = f >> 3, c8 = (f & 7) << 3;
      const int lb = (it * 256 + w * 64) * 8;  // wave-uniform LDS base (elements)
      async16(A + (arow0 + r) * K + ks + c8, &As[lb]);
      async16(B + (brow0 + r) * K + ks + c8, &Bs[lb]);
    }
    __syncthreads();
#pragma unroll
    for (int kk = 0; kk < 2; ++kk) {
      bf16x8 af[4], bfr[4];
#pragma unroll
      for (int i = 0; i < 4; ++i)
        af[i] = ldfrag(&As[(wm * 64 + i * 16 + l15) * 64 + kk * 32 + g * 8]);
#pragma unroll
      for (int j = 0; j < 4; ++j)
        bfr[j] = ldfrag(&Bs[(wn * 64 + j * 16 + l15) * 64 + kk * 32 + g * 8]);
#pragma unroll
      for (int i = 0; i < 4; ++i)
#pragma unroll
        for (int j = 0; j < 4; ++j)
          acc[i][j] = mfma16(af[i], bfr[j], acc[i][j]);
    }
  }
  // epilogue
#pragma unroll
  for (int i = 0; i < 4; ++i) {
#pragma unroll
    for (int j = 0; j < 4; ++j) {
#pragma unroll
      for (int r = 0; r < 4; ++r) {
        const int row = (int)arow0 + wm * 64 + i * 16 + g * 4 + r;
        const int col = (int)brow0 + wn * 64 + j * 16 + l15;
        float v = acc[i][j][r] + bias[col];
        if (MODE == 0) {
          outb[(size_t)row * NQKV + col] = f2bf(v);
        } else if (MODE == 1) {
          if (row < MV) {
            int win = row / 196, t = row - win * 196;
            int b = win / 25, wi = win - b * 25;
            int wr = wi / 5, wc = wi - wr * 5;
            int hh = wr * 14 + t / 14, ww = wc * 14 + (t - (t / 14) * 14);
            if (hh < HW && ww < HW) {
              size_t di = ((size_t)b * 4096 + hh * 64 + ww) * 384 + col;
              auxw[di] = auxr[di] + v;
            }
          }
        } else if (MODE == 2) {
          float gl = 0.5f * v * (1.0f + erff(v * 0.7071067811865475f));
          outb[(size_t)row * HIDD + col] = f2bf(gl);
        } else {
          size_t di = (size_t)row * 384 + col;
          auxw[di] = auxr[di] + v;
        }
      }
    }
  }
}

// ---------- launcher ----------
extern "C" void kernel_launch(void* const* d_in, const int* in_sizes, int n_in,
                              void* d_out, int out_size, void* d_ws, size_t ws_size,
                              hipStream_t stream) {
  const float* x = (const float*)d_in[0];
  const float* ln_attn_w = (const float*)d_in[1];
  const float* ln_attn_b = (const float*)d_in[2];
  const float* qkv_w = (const float*)d_in[3];
  const float* qkv_b = (const float*)d_in[4];
  const float* proj_w = (const float*)d_in[5];
  const float* proj_b = (const float*)d_in[6];
  const float* attn_biases = (const float*)d_in[7];
  const float* conv_w = (const float*)d_in[8];
  const float* bn_w = (const float*)d_in[9];
  const float* bn_b = (const float*)d_in[10];
  const float* bn_mean = (const float*)d_in[11];
  const float* bn_var = (const float*)d_in[12];
  const float* ln_mlp_w = (const float*)d_in[13];
  const float* ln_mlp_b = (const float*)d_in[14];
  const float* fc1_w = (const float*)d_in[15];
  const float* fc1_b = (const float*)d_in[16];
  const float* fc2_w = (const float*)d_in[17];
  const float* fc2_b = (const float*)d_in[18];
  const int* bias_idx = (const int*)d_in[19];

  char* ws = (char*)d_ws;
  size_t off = 0;
  auto alloc = [&](size_t n) {
    void* p = ws + off;
    off = (off + n + 255) & ~(size_t)255;
    return p;
  };
  unsigned short* xn = (unsigned short*)alloc((size_t)MPAD * CDIM * 2);       // reused as xln
  unsigned short* qkv = (unsigned short*)alloc((size_t)MMLP * HIDD * 2);      // reused as h
  unsigned short* attn = (unsigned short*)alloc((size_t)MMLP * CDIM * 4);     // reused as x2 (f32)
  float* x1 = (float*)alloc((size_t)MMLP * CDIM * 4);
  unsigned short* wq = (unsigned short*)alloc((size_t)NQKV * CDIM * 2);
  unsigned short* wp = (unsigned short*)alloc((size_t)CDIM * CDIM * 2);
  unsigned short* w1 = (unsigned short*)alloc((size_t)HIDD * CDIM * 2);
  unsigned short* w2 = (unsigned short*)alloc((size_t)CDIM * HIDD * 2);
  float* biasmat = (float*)alloc((size_t)HEADS * NTOK * NTOK * 4);
  unsigned short* hbuf = qkv;
  float* x2 = (float*)attn;
  unsigned short* xln = xn;
  int n_off = in_sizes[7] / HEADS;

  dim3 B256(256);
  k_cvt<<<dim3((NQKV * CDIM + 255) / 256), B256, 0, stream>>>(qkv_w, wq, NQKV * CDIM);
  k_cvt<<<dim3((CDIM * CDIM + 255) / 256), B256, 0, stream>>>(proj_w, wp, CDIM * CDIM);
  k_cvt<<<dim3((HIDD * CDIM + 255) / 256), B256, 0, stream>>>(fc1_w, w1, HIDD * CDIM);
  k_cvt<<<dim3((CDIM * HIDD + 255) / 256), B256, 0, stream>>>(fc2_w, w2, CDIM * HIDD);
  k_bias<<<dim3((HEADS * NTOK * NTOK + 255) / 256), B256, 0, stream>>>(attn_biases, bias_idx, biasmat, n_off);
  k_ln<1><<<dim3(MPAD / 4), B256, 0, stream>>>(x, ln_attn_w, ln_attn_b, xn);
  k_gemm<0><<<dim3(MPAD / 128, NQKV / 128), B256, 0, stream>>>(xn, wq, qkv_b, nullptr, nullptr, qkv, CDIM);
  k_attn<<<dim3(NWIN * HEADS), B256, 0, stream>>>(qkv, biasmat, attn);
  k_gemm<1><<<dim3(MPAD / 128, CDIM / 128), B256, 0, stream>>>(attn, wp, proj_b, x, x1, nullptr, CDIM);
  k_conv<<<dim3(CBATCH * HW * CDIM / 256), B256, 0, stream>>>(x1, conv_w, bn_w, bn_b, bn_mean, bn_var, x2);
  k_ln<0><<<dim3(MMLP / 4), B256, 0, stream>>>(x2, ln_mlp_w, ln_mlp_b, xln);
  k_gemm<2><<<dim3(MMLP / 128, HIDD / 128), B256, 0, stream>>>(xln, w1, fc1_b, nullptr, nullptr, hbuf, CDIM);
  k_gemm<3><<<dim3(MMLP / 128, CDIM / 128), B256, 0, stream>>>(hbuf, w2, fc2_b, x2, (float*)d_out, nullptr, HIDD);
}

// Round 3
// 630.895 us; speedup vs baseline: 1.3367x; 1.3367x over previous
//
#include <hip/hip_runtime.h>
#include <hip/hip_bf16.h>

#define DI __device__ __forceinline__

typedef __attribute__((ext_vector_type(8))) __bf16 bf16x8;
typedef __attribute__((ext_vector_type(4))) float f32x4;
typedef __attribute__((ext_vector_type(2))) float f32x2;
typedef __attribute__((ext_vector_type(8))) unsigned short us8;
typedef __attribute__((ext_vector_type(4))) unsigned short us4;

// ---- problem constants ----
constexpr int CBATCH = 8;
constexpr int HW = 64;          // H == W
constexpr int CDIM = 384;
constexpr int HEADS = 12;
constexpr int WS = 14;
constexpr int NTOK = 196;       // WS*WS
constexpr int NWIN = 200;       // 8 * 5 * 5
constexpr int MV = 39200;       // NWIN * NTOK
constexpr int MPAD = 39296;     // 307 * 128
constexpr int NQKV = 1152;
constexpr int HIDD = 1536;
constexpr int MMLP = 32768;     // 8 * 4096
constexpr int NBIAS = 12 * 13 * 13 * 4 * 16 * 4;  // tiled bias elements
constexpr float SCALE = 0.17677669529663687f;  // 32^-0.5

DI unsigned short f2bf(float f) { __bf16 b = (__bf16)f; return __builtin_bit_cast(unsigned short, b); }
DI float bf2f(unsigned short u) { unsigned x = (unsigned)u << 16; return __builtin_bit_cast(float, x); }
DI bf16x8 ldfrag(const unsigned short* p) { return __builtin_bit_cast(bf16x8, *(const us8*)p); }
DI f32x4 mfma16(bf16x8 a, bf16x8 b, f32x4 c) {
  return __builtin_amdgcn_mfma_f32_16x16x32_bf16(a, b, c, 0, 0, 0);
}
DI void async16(const void* g, void* l) {
  __builtin_amdgcn_global_load_lds((const __attribute__((address_space(1))) void*)g,
                                   (__attribute__((address_space(3))) void*)l, 16, 0, 0);
}
// V-tile swizzled element address: Vt[32][256], conflict-free for both
// the transpose staging writes and the k-slice fragment reads.
DI int vt_addr(int d, int t) {
  return d * 256 + (((t & ~7) ^ ((d & 7) << 3) ^ (((d >> 3) & 3) << 5)) | (t & 7));
}

// ---------- small prep kernels ----------
__global__ __launch_bounds__(256) void k_cvt(const float* __restrict__ s,
                                             unsigned short* __restrict__ d, int n) {
  int i = blockIdx.x * 256 + threadIdx.x;
  if (i < n) d[i] = f2bf(s[i]);
}

// tiled bf16 bias: bt[h][qt][kt][g][l15][r], matching the swapped-QK S^T fragment
__global__ __launch_bounds__(256) void k_bias2(const float* __restrict__ ab,
                                               const int* __restrict__ bidx,
                                               unsigned short* __restrict__ bt, int n_off) {
  int i = blockIdx.x * 256 + threadIdx.x;
  if (i >= NBIAS) return;
  int r = i & 3, l15 = (i >> 2) & 15, g = (i >> 6) & 3;
  int j = i >> 8;
  int kt = j % 13;
  int j2 = j / 13;
  int qt = j2 % 13;
  int h = j2 / 13;
  int q = qt * 16 + l15, k = kt * 16 + g * 4 + r;
  float v = 0.f;
  if (q < 196 && k < 196) v = ab[h * n_off + bidx[q * 196 + k]];
  bt[i] = f2bf(v);
}

// ---------- LayerNorm (one wave per row, 6 f32/lane) ----------
template <int WIN>
__global__ __launch_bounds__(256) void k_ln(const float* __restrict__ src,
                                            const float* __restrict__ lw,
                                            const float* __restrict__ lb,
                                            unsigned short* __restrict__ dst) {
  const int row = blockIdx.x * 4 + (threadIdx.x >> 6);
  const int l = threadIdx.x & 63;
  const int c0 = l * 6;
  const float* p;
  bool valid;
  if (WIN) {
    int win = row / 196, t = row - win * 196;
    int b = win / 25, wi = win - b * 25;
    int wr = wi / 5, wc = wi - wr * 5;
    int hh = wr * 14 + t / 14, ww = wc * 14 + (t - (t / 14) * 14);
    valid = (row < MV) && (hh < HW) && (ww < HW);
    p = src + ((size_t)b * 4096 + hh * 64 + ww) * CDIM;
  } else {
    valid = true;
    p = src + (size_t)row * CDIM;
  }
  float v[6];
  if (valid) {
    f32x2 a = *(const f32x2*)(p + c0);
    f32x2 b2 = *(const f32x2*)(p + c0 + 2);
    f32x2 c2 = *(const f32x2*)(p + c0 + 4);
    v[0] = a.x; v[1] = a.y; v[2] = b2.x; v[3] = b2.y; v[4] = c2.x; v[5] = c2.y;
  } else {
#pragma unroll
    for (int k = 0; k < 6; ++k) v[k] = 0.f;
  }
  float s = 0.f, q = 0.f;
#pragma unroll
  for (int k = 0; k < 6; ++k) { s += v[k]; q += v[k] * v[k]; }
#pragma unroll
  for (int m = 1; m <= 32; m <<= 1) {
    s += __shfl_xor(s, m, 64);
    q += __shfl_xor(q, m, 64);
  }
  float mean = s * (1.0f / 384.0f);
  float var = q * (1.0f / 384.0f) - mean * mean;
  float rs = rsqrtf(var + 1e-5f);
#pragma unroll
  for (int k = 0; k < 6; ++k) {
    float y = (v[k] - mean) * rs * lw[c0 + k] + lb[c0 + k];
    dst[(size_t)row * CDIM + c0 + k] = f2bf(y);
  }
}

// ---------- depthwise 3x3 conv + BN ----------
__global__ __launch_bounds__(256) void k_conv(const float* __restrict__ x1,
                                              const float* __restrict__ cw,
                                              const float* __restrict__ bw,
                                              const float* __restrict__ bb,
                                              const float* __restrict__ bm,
                                              const float* __restrict__ bv,
                                              float* __restrict__ x2) {
  int idx = blockIdx.x * 256 + threadIdx.x;  // b*64*384 + x*384 + c
  int c = idx % 384;
  int x = (idx / 384) & 63;
  int b = idx / (384 * 64);
  const float* base = x1 + (size_t)b * 4096 * 384 + c;
  float w[9];
#pragma unroll
  for (int k = 0; k < 9; ++k) w[k] = cw[c * 9 + k];
  float sc = rsqrtf(bv[c] + 1e-5f) * bw[c];
  float sb = bb[c] - bm[c] * sc;
  float t0m = 0.f, t0c = 0.f, t0p = 0.f;
  float t1m, t1c, t1p, t2m, t2c, t2p;
  t1m = (x > 0) ? base[(x - 1) * 384] : 0.f;
  t1c = base[x * 384];
  t1p = (x < 63) ? base[(x + 1) * 384] : 0.f;
  for (int y = 0; y < 64; ++y) {
    if (y < 63) {
      int ro = (y + 1) * 64;
      t2m = (x > 0) ? base[(ro + x - 1) * 384] : 0.f;
      t2c = base[(ro + x) * 384];
      t2p = (x < 63) ? base[(ro + x + 1) * 384] : 0.f;
    } else { t2m = t2c = t2p = 0.f; }
    float o = w[0] * t0m + w[1] * t0c + w[2] * t0p +
              w[3] * t1m + w[4] * t1c + w[5] * t1p +
              w[6] * t2m + w[7] * t2c + w[8] * t2p;
    x2[((size_t)b * 4096 + y * 64 + x) * 384 + c] = o * sc + sb;
    t0m = t1m; t0c = t1c; t0p = t1p;
    t1m = t2m; t1c = t2c; t1p = t2p;
  }
}

// ---------- fused windowed attention: one block per (window, head) ----------
// Swapped QK^T (S^T = mfma(K,Q)): lane owns one q-row (= l15); softmax is a
// per-lane 52-value reduce + 2 shfl_xor. P round-trips through a per-wave
// LDS row (lane-local), V through a bank-conflict-free swizzled tile.
__global__ __launch_bounds__(256) void k_attn(const unsigned short* __restrict__ qkv,
                                              const unsigned short* __restrict__ bias_t,
                                              unsigned short* __restrict__ aout) {
  __shared__ unsigned short Vt[32 * 256];
  __shared__ unsigned short Pl[4][16 * 232];
  const int bid = blockIdx.x;
  const int blk = (bid & 7) * 300 + (bid >> 3);  // XCD swizzle (2400 = 8*300)
  const int win = blk / 12, h = blk - win * 12;
  const int tid = threadIdx.x;
  const int w = tid >> 6, l = tid & 63;
  const int l15 = l & 15, g = l >> 4;
  const unsigned short* qb = qkv + (size_t)win * 196 * 1152 + h * 96;

  // stage V transposed + swizzled (rows t>=196 zeroed, t<224)
  for (int i = tid; i < 896; i += 256) {
    int t = i >> 2, d8 = (i & 3) << 3;
    us8 z = {0, 0, 0, 0, 0, 0, 0, 0};
    if (t < 196) z = *(const us8*)(qb + (size_t)t * 1152 + 64 + d8);
#pragma unroll
    for (int j = 0; j < 8; ++j) Vt[vt_addr(d8 + j, t)] = z[j];
  }
  // zero P pad cols 208..231 (per wave, persists across iterations)
  for (int z = l; z < 16 * 24; z += 64) {
    int rr = z / 24, cc = 208 + (z - rr * 24);
    Pl[w][rr * 232 + cc] = 0;
  }
  __syncthreads();

  const unsigned short* bth = bias_t + (size_t)h * (13 * 13 * 4 * 16 * 4);
  unsigned short* plw = &Pl[w][0];
  for (int qt = w; qt < 13; qt += 4) {
    // Q fragment from global (q pre-scaled by SCALE at the QKV epilogue)
    bf16x8 aq = ldfrag(qb + (size_t)(qt * 16 + l15) * 1152 + g * 8);
    f32x4 s[13];
#pragma unroll
    for (int kt = 0; kt < 13; ++kt) {
      f32x4 zz = {0.f, 0.f, 0.f, 0.f};
      bf16x8 bk = ldfrag(qb + (size_t)(kt * 16 + l15) * 1152 + 32 + g * 8);
      s[kt] = mfma16(bk, aq, zz);  // S^T: col=l15=q, row=g*4+r=k
    }
    // bias add (tiled bf16, one 8B coalesced load per kt) + key mask
#pragma unroll
    for (int kt = 0; kt < 13; ++kt) {
      us4 bb = *(const us4*)(bth + (size_t)(((qt * 13 + kt) * 4 + g) * 16 + l15) * 4);
#pragma unroll
      for (int r = 0; r < 4; ++r) {
        float v = s[kt][r] + bf2f(bb[r]);
        if (kt == 12 && g != 0) v = -1e30f;  // k = 192+g*4+r >= 196
        s[kt][r] = v;
      }
    }
    // softmax over k: per-lane 52 values + cross-g combine
    float m = -1e30f;
#pragma unroll
    for (int kt = 0; kt < 13; ++kt)
#pragma unroll
      for (int r = 0; r < 4; ++r) m = fmaxf(m, s[kt][r]);
    m = fmaxf(m, __shfl_xor(m, 16, 64));
    m = fmaxf(m, __shfl_xor(m, 32, 64));
    float su = 0.f;
#pragma unroll
    for (int kt = 0; kt < 13; ++kt)
#pragma unroll
      for (int r = 0; r < 4; ++r) {
        float p = __expf(s[kt][r] - m);
        s[kt][r] = p;
        su += p;
      }
    su += __shfl_xor(su, 16, 64);
    su += __shfl_xor(su, 32, 64);
    float inv = 1.0f / su;
    // write P rows (lane-own q row = l15), 8B vector stores
#pragma unroll
    for (int kt = 0; kt < 13; ++kt) {
      us4 pk;
#pragma unroll
      for (int r = 0; r < 4; ++r) pk[r] = f2bf(s[kt][r] * inv);
      *(us4*)(plw + l15 * 232 + kt * 16 + g * 4) = pk;
    }
    // PV
    f32x4 o0 = {0.f, 0.f, 0.f, 0.f}, o1 = {0.f, 0.f, 0.f, 0.f};
#pragma unroll
    for (int kc = 0; kc < 7; ++kc) {
      int t0 = kc * 32 + g * 8;
      bf16x8 pa = ldfrag(plw + l15 * 232 + t0);
      bf16x8 b0 = ldfrag(&Vt[vt_addr(l15, t0)]);
      bf16x8 b1 = ldfrag(&Vt[vt_addr(16 + l15, t0)]);
      o0 = mfma16(pa, b0, o0);
      o1 = mfma16(pa, b1, o1);
    }
#pragma unroll
    for (int r = 0; r < 4; ++r) {
      int rw = qt * 16 + g * 4 + r;
      if (rw < 196) {
        size_t rb = ((size_t)win * 196 + rw) * 384 + h * 32;
        aout[rb + l15] = f2bf(o0[r]);
        aout[rb + 16 + l15] = f2bf(o1[r]);
      }
    }
  }
}

// ---------- bf16 GEMM, B^T weights, 128x128 tile, BK=64, templated epilogue ----
// MODE 0: +bias, scale q-cols by SCALE -> bf16 out (stride NQKV)
// MODE 1: +bias, window-reverse scatter, x1 = x + val (f32)
// MODE 2: +bias, exact GELU -> bf16 out (stride HIDD)
// MODE 3: +bias, out = auxr + val (f32, stride 384)
template <int MODE>
__global__ __launch_bounds__(256) void k_gemm(const unsigned short* __restrict__ A,
                                              const unsigned short* __restrict__ B,
                                              const float* __restrict__ bias,
                                              const float* __restrict__ auxr,
                                              float* __restrict__ auxw,
                                              unsigned short* __restrict__ outb,
                                              int K) {
  __shared__ unsigned short As[128 * 64];
  __shared__ unsigned short Bs[128 * 64];
  const int tid = threadIdx.x;
  const int w = tid >> 6, l = tid & 63;
  const int l15 = l & 15, g = l >> 4;
  const int wm = w >> 1, wn = w & 1;
  const size_t arow0 = (size_t)blockIdx.x * 128;
  const size_t brow0 = (size_t)blockIdx.y * 128;
  f32x4 acc[4][4] = {};
  for (int ks = 0; ks < K; ks += 64) {
    if (ks) __syncthreads();
#pragma unroll
    for (int it = 0; it < 4; ++it) {
      const int f = it * 256 + tid;
      const int r = f >> 3, c8 = (f & 7) << 3;
      const int lb = (it * 256 + w * 64) * 8;  // wave-uniform LDS base (elements)
      async16(A + (arow0 + r) * K + ks + c8, &As[lb]);
      async16(B + (brow0 + r) * K + ks + c8, &Bs[lb]);
    }
    __syncthreads();
#pragma unroll
    for (int kk = 0; kk < 2; ++kk) {
      bf16x8 af[4], bfr[4];
#pragma unroll
      for (int i = 0; i < 4; ++i)
        af[i] = ldfrag(&As[(wm * 64 + i * 16 + l15) * 64 + kk * 32 + g * 8]);
#pragma unroll
      for (int j = 0; j < 4; ++j)
        bfr[j] = ldfrag(&Bs[(wn * 64 + j * 16 + l15) * 64 + kk * 32 + g * 8]);
#pragma unroll
      for (int i = 0; i < 4; ++i)
#pragma unroll
        for (int j = 0; j < 4; ++j)
          acc[i][j] = mfma16(af[i], bfr[j], acc[i][j]);
    }
  }
  // epilogue
#pragma unroll
  for (int i = 0; i < 4; ++i) {
#pragma unroll
    for (int j = 0; j < 4; ++j) {
#pragma unroll
      for (int r = 0; r < 4; ++r) {
        const int row = (int)arow0 + wm * 64 + i * 16 + g * 4 + r;
        const int col = (int)brow0 + wn * 64 + j * 16 + l15;
        float v = acc[i][j][r] + bias[col];
        if (MODE == 0) {
          int ch = col % 96;
          float o = (ch < 32) ? v * SCALE : v;  // pre-scale q
          outb[(size_t)row * NQKV + col] = f2bf(o);
        } else if (MODE == 1) {
          if (row < MV) {
            int win = row / 196, t = row - win * 196;
            int b = win / 25, wi = win - b * 25;
            int wr = wi / 5, wc = wi - wr * 5;
            int hh = wr * 14 + t / 14, ww = wc * 14 + (t - (t / 14) * 14);
            if (hh < HW && ww < HW) {
              size_t di = ((size_t)b * 4096 + hh * 64 + ww) * 384 + col;
              auxw[di] = auxr[di] + v;
            }
          }
        } else if (MODE == 2) {
          float gl = 0.5f * v * (1.0f + erff(v * 0.7071067811865475f));
          outb[(size_t)row * HIDD + col] = f2bf(gl);
        } else {
          size_t di = (size_t)row * 384 + col;
          auxw[di] = auxr[di] + v;
        }
      }
    }
  }
}

// ---------- launcher ----------
extern "C" void kernel_launch(void* const* d_in, const int* in_sizes, int n_in,
                              void* d_out, int out_size, void* d_ws, size_t ws_size,
                              hipStream_t stream) {
  const float* x = (const float*)d_in[0];
  const float* ln_attn_w = (const float*)d_in[1];
  const float* ln_attn_b = (const float*)d_in[2];
  const float* qkv_w = (const float*)d_in[3];
  const float* qkv_b = (const float*)d_in[4];
  const float* proj_w = (const float*)d_in[5];
  const float* proj_b = (const float*)d_in[6];
  const float* attn_biases = (const float*)d_in[7];
  const float* conv_w = (const float*)d_in[8];
  const float* bn_w = (const float*)d_in[9];
  const float* bn_b = (const float*)d_in[10];
  const float* bn_mean = (const float*)d_in[11];
  const float* bn_var = (const float*)d_in[12];
  const float* ln_mlp_w = (const float*)d_in[13];
  const float* ln_mlp_b = (const float*)d_in[14];
  const float* fc1_w = (const float*)d_in[15];
  const float* fc1_b = (const float*)d_in[16];
  const float* fc2_w = (const float*)d_in[17];
  const float* fc2_b = (const float*)d_in[18];
  const int* bias_idx = (const int*)d_in[19];

  char* ws = (char*)d_ws;
  size_t off = 0;
  auto alloc = [&](size_t n) {
    void* p = ws + off;
    off = (off + n + 255) & ~(size_t)255;
    return p;
  };
  unsigned short* xn = (unsigned short*)alloc((size_t)MPAD * CDIM * 2);       // reused as xln
  unsigned short* qkv = (unsigned short*)alloc((size_t)MMLP * HIDD * 2);      // reused as h
  unsigned short* attn = (unsigned short*)alloc((size_t)MMLP * CDIM * 4);     // reused as x2 (f32)
  float* x1 = (float*)alloc((size_t)MMLP * CDIM * 4);
  unsigned short* wq = (unsigned short*)alloc((size_t)NQKV * CDIM * 2);
  unsigned short* wp = (unsigned short*)alloc((size_t)CDIM * CDIM * 2);
  unsigned short* w1 = (unsigned short*)alloc((size_t)HIDD * CDIM * 2);
  unsigned short* w2 = (unsigned short*)alloc((size_t)CDIM * HIDD * 2);
  unsigned short* bias_t = (unsigned short*)alloc((size_t)NBIAS * 2);
  unsigned short* hbuf = qkv;
  float* x2 = (float*)attn;
  unsigned short* xln = xn;
  int n_off = in_sizes[7] / HEADS;

  dim3 B256(256);
  k_cvt<<<dim3((NQKV * CDIM + 255) / 256), B256, 0, stream>>>(qkv_w, wq, NQKV * CDIM);
  k_cvt<<<dim3((CDIM * CDIM + 255) / 256), B256, 0, stream>>>(proj_w, wp, CDIM * CDIM);
  k_cvt<<<dim3((HIDD * CDIM + 255) / 256), B256, 0, stream>>>(fc1_w, w1, HIDD * CDIM);
  k_cvt<<<dim3((CDIM * HIDD + 255) / 256), B256, 0, stream>>>(fc2_w, w2, CDIM * HIDD);
  k_bias2<<<dim3((NBIAS + 255) / 256), B256, 0, stream>>>(attn_biases, bias_idx, bias_t, n_off);
  k_ln<1><<<dim3(MPAD / 4), B256, 0, stream>>>(x, ln_attn_w, ln_attn_b, xn);
  k_gemm<0><<<dim3(MPAD / 128, NQKV / 128), B256, 0, stream>>>(xn, wq, qkv_b, nullptr, nullptr, qkv, CDIM);
  k_attn<<<dim3(NWIN * HEADS), B256, 0, stream>>>(qkv, bias_t, attn);
  k_gemm<1><<<dim3(MPAD / 128, CDIM / 128), B256, 0, stream>>>(attn, wp, proj_b, x, x1, nullptr, CDIM);
  k_conv<<<dim3(CBATCH * HW * CDIM / 256), B256, 0, stream>>>(x1, conv_w, bn_w, bn_b, bn_mean, bn_var, x2);
  k_ln<0><<<dim3(MMLP / 4), B256, 0, stream>>>(x2, ln_mlp_w, ln_mlp_b, xln);
  k_gemm<2><<<dim3(MMLP / 128, HIDD / 128), B256, 0, stream>>>(xln, w1, fc1_b, nullptr, nullptr, hbuf, CDIM);
  k_gemm<3><<<dim3(MMLP / 128, CDIM / 128), B256, 0, stream>>>(hbuf, w2, fc2_b, x2, (float*)d_out, nullptr, HIDD);
}

// Round 4
// 617.222 us; speedup vs baseline: 1.3663x; 1.0222x over previous
//
#include <hip/hip_runtime.h>
#include <hip/hip_bf16.h>

#define DI __device__ __forceinline__

typedef __attribute__((ext_vector_type(8))) __bf16 bf16x8;
typedef __attribute__((ext_vector_type(4))) float f32x4;
typedef __attribute__((ext_vector_type(2))) float f32x2;
typedef __attribute__((ext_vector_type(8))) unsigned short us8;
typedef __attribute__((ext_vector_type(4))) unsigned short us4;

// ---- problem constants ----
constexpr int CBATCH = 8;
constexpr int HW = 64;          // H == W
constexpr int CDIM = 384;
constexpr int HEADS = 12;
constexpr int WS = 14;
constexpr int NTOK = 196;       // WS*WS
constexpr int NWIN = 200;       // 8 * 5 * 5
constexpr int MV = 39200;       // NWIN * NTOK
constexpr int MPAD = 39296;     // 307 * 128
constexpr int NQKV = 1152;
constexpr int HIDD = 1536;
constexpr int MMLP = 32768;     // 8 * 4096
constexpr int NBIAS = 12 * 13 * 13 * 4 * 16 * 4;  // tiled bias elements
constexpr int PLSTR = 228;      // P LDS row stride (16 distinct banks for b64/b128)
constexpr float SCALE = 0.17677669529663687f;  // 32^-0.5

DI unsigned short f2bf(float f) { __bf16 b = (__bf16)f; return __builtin_bit_cast(unsigned short, b); }
DI bf16x8 ldfrag(const unsigned short* p) { return __builtin_bit_cast(bf16x8, *(const us8*)p); }
DI f32x4 mfma16(bf16x8 a, bf16x8 b, f32x4 c) {
  return __builtin_amdgcn_mfma_f32_16x16x32_bf16(a, b, c, 0, 0, 0);
}
DI void async16(const void* g, void* l) {
  __builtin_amdgcn_global_load_lds((const __attribute__((address_space(1))) void*)g,
                                   (__attribute__((address_space(3))) void*)l, 16, 0, 0);
}
// V-tile swizzled element address: Vt[32][256], conflict-free for both
// the transpose staging writes and the k-slice fragment reads.
DI int vt_addr(int d, int t) {
  return d * 256 + (((t & ~7) ^ ((d & 7) << 3) ^ (((d >> 3) & 3) << 5)) | (t & 7));
}

// ---------- small prep kernels ----------
__global__ __launch_bounds__(256) void k_cvt(const float* __restrict__ s,
                                             unsigned short* __restrict__ d, int n) {
  int i = blockIdx.x * 256 + threadIdx.x;
  if (i < n) d[i] = f2bf(s[i]);
}

// tiled f32 bias: bt[h][qt][kt][g][l15][r], matching the swapped-QK S^T fragment
__global__ __launch_bounds__(256) void k_bias2(const float* __restrict__ ab,
                                               const int* __restrict__ bidx,
                                               float* __restrict__ bt, int n_off) {
  int i = blockIdx.x * 256 + threadIdx.x;
  if (i >= NBIAS) return;
  int r = i & 3, l15 = (i >> 2) & 15, g = (i >> 6) & 3;
  int j = i >> 8;
  int kt = j % 13;
  int j2 = j / 13;
  int qt = j2 % 13;
  int h = j2 / 13;
  int q = qt * 16 + l15, k = kt * 16 + g * 4 + r;
  float v = 0.f;
  if (q < 196 && k < 196) v = ab[h * n_off + bidx[q * 196 + k]];
  bt[i] = v;
}

// ---------- LayerNorm (one wave per row, 6 f32/lane) ----------
template <int WIN>
__global__ __launch_bounds__(256) void k_ln(const float* __restrict__ src,
                                            const float* __restrict__ lw,
                                            const float* __restrict__ lb,
                                            unsigned short* __restrict__ dst) {
  const int row = blockIdx.x * 4 + (threadIdx.x >> 6);
  const int l = threadIdx.x & 63;
  const int c0 = l * 6;
  const float* p;
  bool valid;
  if (WIN) {
    int win = row / 196, t = row - win * 196;
    int b = win / 25, wi = win - b * 25;
    int wr = wi / 5, wc = wi - wr * 5;
    int hh = wr * 14 + t / 14, ww = wc * 14 + (t - (t / 14) * 14);
    valid = (row < MV) && (hh < HW) && (ww < HW);
    p = src + ((size_t)b * 4096 + hh * 64 + ww) * CDIM;
  } else {
    valid = true;
    p = src + (size_t)row * CDIM;
  }
  float v[6];
  if (valid) {
    f32x2 a = *(const f32x2*)(p + c0);
    f32x2 b2 = *(const f32x2*)(p + c0 + 2);
    f32x2 c2 = *(const f32x2*)(p + c0 + 4);
    v[0] = a.x; v[1] = a.y; v[2] = b2.x; v[3] = b2.y; v[4] = c2.x; v[5] = c2.y;
  } else {
#pragma unroll
    for (int k = 0; k < 6; ++k) v[k] = 0.f;
  }
  float s = 0.f, q = 0.f;
#pragma unroll
  for (int k = 0; k < 6; ++k) { s += v[k]; q += v[k] * v[k]; }
#pragma unroll
  for (int m = 1; m <= 32; m <<= 1) {
    s += __shfl_xor(s, m, 64);
    q += __shfl_xor(q, m, 64);
  }
  float mean = s * (1.0f / 384.0f);
  float var = q * (1.0f / 384.0f) - mean * mean;
  float rs = rsqrtf(var + 1e-5f);
#pragma unroll
  for (int k = 0; k < 6; ++k) {
    float y = (v[k] - mean) * rs * lw[c0 + k] + lb[c0 + k];
    dst[(size_t)row * CDIM + c0 + k] = f2bf(y);
  }
}

// ---------- depthwise 3x3 conv + BN ----------
__global__ __launch_bounds__(256) void k_conv(const float* __restrict__ x1,
                                              const float* __restrict__ cw,
                                              const float* __restrict__ bw,
                                              const float* __restrict__ bb,
                                              const float* __restrict__ bm,
                                              const float* __restrict__ bv,
                                              float* __restrict__ x2) {
  int idx = blockIdx.x * 256 + threadIdx.x;  // b*64*384 + x*384 + c
  int c = idx % 384;
  int x = (idx / 384) & 63;
  int b = idx / (384 * 64);
  const float* base = x1 + (size_t)b * 4096 * 384 + c;
  float w[9];
#pragma unroll
  for (int k = 0; k < 9; ++k) w[k] = cw[c * 9 + k];
  float sc = rsqrtf(bv[c] + 1e-5f) * bw[c];
  float sb = bb[c] - bm[c] * sc;
  float t0m = 0.f, t0c = 0.f, t0p = 0.f;
  float t1m, t1c, t1p, t2m, t2c, t2p;
  t1m = (x > 0) ? base[(x - 1) * 384] : 0.f;
  t1c = base[x * 384];
  t1p = (x < 63) ? base[(x + 1) * 384] : 0.f;
  for (int y = 0; y < 64; ++y) {
    if (y < 63) {
      int ro = (y + 1) * 64;
      t2m = (x > 0) ? base[(ro + x - 1) * 384] : 0.f;
      t2c = base[(ro + x) * 384];
      t2p = (x < 63) ? base[(ro + x + 1) * 384] : 0.f;
    } else { t2m = t2c = t2p = 0.f; }
    float o = w[0] * t0m + w[1] * t0c + w[2] * t0p +
              w[3] * t1m + w[4] * t1c + w[5] * t1p +
              w[6] * t2m + w[7] * t2c + w[8] * t2p;
    x2[((size_t)b * 4096 + y * 64 + x) * 384 + c] = o * sc + sb;
    t0m = t1m; t0c = t1c; t0p = t1p;
    t1m = t2m; t1c = t2c; t1p = t2p;
  }
}

// ---------- fused windowed attention: one block per (window, head) ----------
// Swapped QK^T (S^T = mfma(K,Q)), STREAMING softmax: per-kt MFMA -> +bias(f32)
// -> exp (no max-subtract; scores bounded ~|2|) -> bf16 pack -> LDS. Only the
// running sum su stays live -> low VGPR -> 4 waves/EU. Normalization deferred
// to the output (O = sum(P~V)/su).
__global__ __launch_bounds__(256, 4) void k_attn(const unsigned short* __restrict__ qkv,
                                                 const float* __restrict__ bias_f,
                                                 unsigned short* __restrict__ aout) {
  __shared__ unsigned short Vt[32 * 256];
  __shared__ unsigned short Pl[4][16 * PLSTR];
  const int bid = blockIdx.x;
  const int blk = (bid & 7) * 300 + (bid >> 3);  // XCD swizzle (2400 = 8*300)
  const int win = blk / 12, h = blk - win * 12;
  const int tid = threadIdx.x;
  const int w = tid >> 6, l = tid & 63;
  const int l15 = l & 15, g = l >> 4;
  const unsigned short* qb = qkv + (size_t)win * 196 * 1152 + h * 96;

  // stage V transposed + swizzled (rows t>=196 zeroed, t<224)
  for (int i = tid; i < 896; i += 256) {
    int t = i >> 2, d8 = (i & 3) << 3;
    us8 z = {0, 0, 0, 0, 0, 0, 0, 0};
    if (t < 196) z = *(const us8*)(qb + (size_t)t * 1152 + 64 + d8);
#pragma unroll
    for (int j = 0; j < 8; ++j) Vt[vt_addr(d8 + j, t)] = z[j];
  }
  // zero P pad cols 208..227 (per wave, persists across iterations)
  for (int z = l; z < 16 * 20; z += 64) {
    int rr = z / 20, cc = 208 + (z - rr * 20);
    Pl[w][rr * PLSTR + cc] = 0;
  }
  __syncthreads();

  const float* bth = bias_f + (size_t)h * (13 * 13 * 4 * 16 * 4);
  unsigned short* plw = &Pl[w][0];
  for (int qt = w; qt < 13; qt += 4) {
    // Q fragment from global (q pre-scaled by SCALE at the QKV epilogue)
    bf16x8 aq = ldfrag(qb + (size_t)(qt * 16 + l15) * 1152 + g * 8);
    float su = 0.f;
#pragma unroll
    for (int kt = 0; kt < 13; ++kt) {
      f32x4 zz = {0.f, 0.f, 0.f, 0.f};
      bf16x8 bk = ldfrag(qb + (size_t)(kt * 16 + l15) * 1152 + 32 + g * 8);
      f32x4 s = mfma16(bk, aq, zz);  // S^T: col=l15=q, row=g*4+r=k
      f32x4 bb = *(const f32x4*)(bth + (size_t)(((qt * 13 + kt) * 4 + g) * 16 + l15) * 4);
      us4 pk;
#pragma unroll
      for (int r = 0; r < 4; ++r) {
        float p = __expf(s[r] + bb[r]);
        if (kt == 12 && g != 0) p = 0.f;  // k = 192+g*4+r >= 196
        su += p;
        pk[r] = f2bf(p);
      }
      *(us4*)(plw + l15 * PLSTR + kt * 16 + g * 4) = pk;
    }
    su += __shfl_xor(su, 16, 64);
    su += __shfl_xor(su, 32, 64);
    asm volatile("s_waitcnt lgkmcnt(0)" ::: "memory");
    __builtin_amdgcn_sched_barrier(0);
    // PV (P unnormalized)
    f32x4 o0 = {0.f, 0.f, 0.f, 0.f}, o1 = {0.f, 0.f, 0.f, 0.f};
#pragma unroll
    for (int kc = 0; kc < 7; ++kc) {
      int t0 = kc * 32 + g * 8;
      bf16x8 pa = ldfrag(plw + l15 * PLSTR + t0);
      bf16x8 b0 = ldfrag(&Vt[vt_addr(l15, t0)]);
      bf16x8 b1 = ldfrag(&Vt[vt_addr(16 + l15, t0)]);
      o0 = mfma16(pa, b0, o0);
      o1 = mfma16(pa, b1, o1);
    }
    float inv = 1.0f / su;
#pragma unroll
    for (int r = 0; r < 4; ++r) {
      int rw = qt * 16 + g * 4 + r;
      if (rw < 196) {
        size_t rb = ((size_t)win * 196 + rw) * 384 + h * 32;
        aout[rb + l15] = f2bf(o0[r] * inv);
        aout[rb + 16 + l15] = f2bf(o1[r] * inv);
      }
    }
  }
}

// ---------- bf16 GEMM, B^T weights, 128x128 tile, BK=64, templated epilogue ----
// MODE 0: +bias, scale q-cols by SCALE -> bf16 out (stride NQKV)
// MODE 1: +bias, window-reverse scatter, x1 = x + val (f32)
// MODE 2: +bias, exact GELU -> bf16 out (stride HIDD)
// MODE 3: +bias, out = auxr + val (f32, stride 384)
template <int MODE>
__global__ __launch_bounds__(256) void k_gemm(const unsigned short* __restrict__ A,
                                              const unsigned short* __restrict__ B,
                                              const float* __restrict__ bias,
                                              const float* __restrict__ auxr,
                                              float* __restrict__ auxw,
                                              unsigned short* __restrict__ outb,
                                              int K) {
  __shared__ unsigned short As[128 * 64];
  __shared__ unsigned short Bs[128 * 64];
  const int tid = threadIdx.x;
  const int w = tid >> 6, l = tid & 63;
  const int l15 = l & 15, g = l >> 4;
  const int wm = w >> 1, wn = w & 1;
  const size_t arow0 = (size_t)blockIdx.x * 128;
  const size_t brow0 = (size_t)blockIdx.y * 128;
  f32x4 acc[4][4] = {};
  for (int ks = 0; ks < K; ks += 64) {
    if (ks) __syncthreads();
#pragma unroll
    for (int it = 0; it < 4; ++it) {
      const int f = it * 256 + tid;
      const int r = f >> 3, c8 = (f & 7) << 3;
      const int lb = (it * 256 + w * 64) * 8;  // wave-uniform LDS base (elements)
      async16(A + (arow0 + r) * K + ks + c8, &As[lb]);
      async16(B + (brow0 + r) * K + ks + c8, &Bs[lb]);
    }
    __syncthreads();
#pragma unroll
    for (int kk = 0; kk < 2; ++kk) {
      bf16x8 af[4], bfr[4];
#pragma unroll
      for (int i = 0; i < 4; ++i)
        af[i] = ldfrag(&As[(wm * 64 + i * 16 + l15) * 64 + kk * 32 + g * 8]);
#pragma unroll
      for (int j = 0; j < 4; ++j)
        bfr[j] = ldfrag(&Bs[(wn * 64 + j * 16 + l15) * 64 + kk * 32 + g * 8]);
#pragma unroll
      for (int i = 0; i < 4; ++i)
#pragma unroll
        for (int j = 0; j < 4; ++j)
          acc[i][j] = mfma16(af[i], bfr[j], acc[i][j]);
    }
  }
  // epilogue
#pragma unroll
  for (int i = 0; i < 4; ++i) {
#pragma unroll
    for (int j = 0; j < 4; ++j) {
#pragma unroll
      for (int r = 0; r < 4; ++r) {
        const int row = (int)arow0 + wm * 64 + i * 16 + g * 4 + r;
        const int col = (int)brow0 + wn * 64 + j * 16 + l15;
        float v = acc[i][j][r] + bias[col];
        if (MODE == 0) {
          int ch = col % 96;
          float o = (ch < 32) ? v * SCALE : v;  // pre-scale q
          outb[(size_t)row * NQKV + col] = f2bf(o);
        } else if (MODE == 1) {
          if (row < MV) {
            int win = row / 196, t = row - win * 196;
            int b = win / 25, wi = win - b * 25;
            int wr = wi / 5, wc = wi - wr * 5;
            int hh = wr * 14 + t / 14, ww = wc * 14 + (t - (t / 14) * 14);
            if (hh < HW && ww < HW) {
              size_t di = ((size_t)b * 4096 + hh * 64 + ww) * 384 + col;
              auxw[di] = auxr[di] + v;
            }
          }
        } else if (MODE == 2) {
          float gl = 0.5f * v * (1.0f + erff(v * 0.7071067811865475f));
          outb[(size_t)row * HIDD + col] = f2bf(gl);
        } else {
          size_t di = (size_t)row * 384 + col;
          auxw[di] = auxr[di] + v;
        }
      }
    }
  }
}

// ---------- launcher ----------
extern "C" void kernel_launch(void* const* d_in, const int* in_sizes, int n_in,
                              void* d_out, int out_size, void* d_ws, size_t ws_size,
                              hipStream_t stream) {
  const float* x = (const float*)d_in[0];
  const float* ln_attn_w = (const float*)d_in[1];
  const float* ln_attn_b = (const float*)d_in[2];
  const float* qkv_w = (const float*)d_in[3];
  const float* qkv_b = (const float*)d_in[4];
  const float* proj_w = (const float*)d_in[5];
  const float* proj_b = (const float*)d_in[6];
  const float* attn_biases = (const float*)d_in[7];
  const float* conv_w = (const float*)d_in[8];
  const float* bn_w = (const float*)d_in[9];
  const float* bn_b = (const float*)d_in[10];
  const float* bn_mean = (const float*)d_in[11];
  const float* bn_var = (const float*)d_in[12];
  const float* ln_mlp_w = (const float*)d_in[13];
  const float* ln_mlp_b = (const float*)d_in[14];
  const float* fc1_w = (const float*)d_in[15];
  const float* fc1_b = (const float*)d_in[16];
  const float* fc2_w = (const float*)d_in[17];
  const float* fc2_b = (const float*)d_in[18];
  const int* bias_idx = (const int*)d_in[19];

  char* ws = (char*)d_ws;
  size_t off = 0;
  auto alloc = [&](size_t n) {
    void* p = ws + off;
    off = (off + n + 255) & ~(size_t)255;
    return p;
  };
  unsigned short* xn = (unsigned short*)alloc((size_t)MPAD * CDIM * 2);       // reused as xln
  unsigned short* qkv = (unsigned short*)alloc((size_t)MMLP * HIDD * 2);      // reused as h
  unsigned short* attn = (unsigned short*)alloc((size_t)MMLP * CDIM * 4);     // reused as x2 (f32)
  float* x1 = (float*)alloc((size_t)MMLP * CDIM * 4);
  unsigned short* wq = (unsigned short*)alloc((size_t)NQKV * CDIM * 2);
  unsigned short* wp = (unsigned short*)alloc((size_t)CDIM * CDIM * 2);
  unsigned short* w1 = (unsigned short*)alloc((size_t)HIDD * CDIM * 2);
  unsigned short* w2 = (unsigned short*)alloc((size_t)CDIM * HIDD * 2);
  float* bias_f = (float*)alloc((size_t)NBIAS * 4);
  unsigned short* hbuf = qkv;
  float* x2 = (float*)attn;
  unsigned short* xln = xn;
  int n_off = in_sizes[7] / HEADS;

  dim3 B256(256);
  k_cvt<<<dim3((NQKV * CDIM + 255) / 256), B256, 0, stream>>>(qkv_w, wq, NQKV * CDIM);
  k_cvt<<<dim3((CDIM * CDIM + 255) / 256), B256, 0, stream>>>(proj_w, wp, CDIM * CDIM);
  k_cvt<<<dim3((HIDD * CDIM + 255) / 256), B256, 0, stream>>>(fc1_w, w1, HIDD * CDIM);
  k_cvt<<<dim3((CDIM * HIDD + 255) / 256), B256, 0, stream>>>(fc2_w, w2, CDIM * HIDD);
  k_bias2<<<dim3((NBIAS + 255) / 256), B256, 0, stream>>>(attn_biases, bias_idx, bias_f, n_off);
  k_ln<1><<<dim3(MPAD / 4), B256, 0, stream>>>(x, ln_attn_w, ln_attn_b, xn);
  k_gemm<0><<<dim3(MPAD / 128, NQKV / 128), B256, 0, stream>>>(xn, wq, qkv_b, nullptr, nullptr, qkv, CDIM);
  k_attn<<<dim3(NWIN * HEADS), B256, 0, stream>>>(qkv, bias_f, attn);
  k_gemm<1><<<dim3(MPAD / 128, CDIM / 128), B256, 0, stream>>>(attn, wp, proj_b, x, x1, nullptr, CDIM);
  k_conv<<<dim3(CBATCH * HW * CDIM / 256), B256, 0, stream>>>(x1, conv_w, bn_w, bn_b, bn_mean, bn_var, x2);
  k_ln<0><<<dim3(MMLP / 4), B256, 0, stream>>>(x2, ln_mlp_w, ln_mlp_b, xln);
  k_gemm<2><<<dim3(MMLP / 128, HIDD / 128), B256, 0, stream>>>(xln, w1, fc1_b, nullptr, nullptr, hbuf, CDIM);
  k_gemm<3><<<dim3(MMLP / 128, CDIM / 128), B256, 0, stream>>>(hbuf, w2, fc2_b, x2, (float*)d_out, nullptr, HIDD);
}